// Round 6
// baseline (307.816 us; speedup 1.0000x reference)
//
#include <hip/hip_runtime.h>
#include <hip/hip_bf16.h>

#define N_NODES 50000
#define N_EDGES 800000
#define F 128
#define L 64
#define MAXD 128          // ELL row capacity; deg ~ Poisson(16), P(>=128) ~ 1e-60
#define BN_EPS 1e-5f
#define EDGE_BLOCKS 3125  // 800000/256
#define GEMM_BLOCKS 782   // ceil(50000/64)
#define AGG_BLOCKS 12500  // 50000/4

typedef __attribute__((ext_vector_type(8))) short short8;
typedef __attribute__((ext_vector_type(8))) unsigned short ushort8;
typedef __attribute__((ext_vector_type(4))) unsigned short ushortx4;
typedef __attribute__((ext_vector_type(4))) float f32x4;

// ---------------- runtime dtype adaptivity ----------------
// flags[0] = 1 if float inputs are fp32, 0 if bf16
// flags[1] = 1 if edge_index is int64, 0 if int32
static __device__ __forceinline__ float loadF(const void* p, int i, int f32) {
    if (f32) return ((const float*)p)[i];
    return __bfloat162float(((const __hip_bfloat16*)p)[i]);
}
static __device__ __forceinline__ float bfu2f(unsigned short u) {
    unsigned int t = ((unsigned int)u) << 16;
    float f;
    __builtin_memcpy(&f, &t, 4);
    return f;
}
static __device__ __forceinline__ short f2bf_s(float f) {
    union { __hip_bfloat16 b; short s; } cv;
    cv.b = __float2bfloat16(f);
    return cv.s;
}
static __device__ __forceinline__ unsigned short f2bf_u(float f) {
    union { __hip_bfloat16 b; unsigned short u; } cv;
    cv.b = __float2bfloat16(f);
    return cv.u;
}

// ---- fused prep: [block 0] dtype detect -> flags; [1..64] transpose weights
// (self-detected float dtype); [65..3189] per-edge degree count + DIRECT ELL
// fill: the degree atomic's return value IS the edge's unique slot, so
// csrE[d*MAXD + r] = s immediately — no offsets, no separate fill phase.
// degi must be pre-zeroed (hipMemsetAsync before this kernel). ----
__global__ void k_prep(const void* __restrict__ W1, const void* __restrict__ Wmu,
                       const void* __restrict__ Wls, const unsigned short* __restrict__ xs,
                       const void* __restrict__ ei, __hip_bfloat16* __restrict__ Wt1,
                       __hip_bfloat16* __restrict__ Wt2, int* __restrict__ flags,
                       int* __restrict__ degi, int* __restrict__ csrE) {
    int b = blockIdx.x;
    int t = threadIdx.x;
    if (b == 0) {
        __shared__ int cnt[2];
        if (t < 2) cnt[t] = 0;
        __syncthreads();
        unsigned short v = xs[2 * t];
        int e = (v >> 7) & 0xff;
        int sane = (e >= 112 && e <= 133) ? 1 : 0;
        if (v == 0 || v == 0x8000) sane = 1;
        atomicAdd(&cnt[0], sane);
        atomicAdd(&cnt[1], (((const int*)ei)[2 * t + 1] != 0) ? 1 : 0);
        __syncthreads();
        if (t == 0) {
            flags[0] = (cnt[0] < 128) ? 1 : 0;  // few sane bf16 patterns => fp32
            flags[1] = (cnt[1] < 8) ? 1 : 0;    // all-zero odd slots => int64
        }
    } else if (b <= 64) {
        // self-detect float dtype from W1 bit patterns (sigma~0.09 => sane bf16 exps)
        __shared__ int cnt;
        if (t == 0) cnt = 0;
        __syncthreads();
        unsigned short v = ((const unsigned short*)W1)[2 * t];
        int e = (v >> 7) & 0xff;
        atomicAdd(&cnt, (e >= 100 && e <= 133) ? 1 : 0);
        __syncthreads();
        int f32 = (cnt < 128) ? 1 : 0;
        int idx = (b - 1) * 256 + t;  // 16384 total
        int n = idx >> 7, k = idx & 127;
        Wt1[idx] = __float2bfloat16(loadF(W1, k * F + n, f32));
        float v2 = (n < L) ? loadF(Wmu, k * L + n, f32) : loadF(Wls, k * L + (n - L), f32);
        Wt2[idx] = __float2bfloat16(v2);
    } else {
        // edge block: self-detect i64 from own window, then degree-count + ELL fill
        int e0 = (b - 65) * 256 + t;  // < 800000 exactly
        __shared__ int nz;
        if (t == 0) nz = 0;
        __syncthreads();
        int w = ((const int*)ei)[2 * e0 + 1];  // i64: high word (0); i32: random ids
        if (w != 0) atomicAdd(&nz, 1);
        __syncthreads();
        int s, d;
        if (nz < 8) {  // int64
            s = (int)((const long long*)ei)[e0];
            d = (int)((const long long*)ei)[N_EDGES + e0];
        } else {
            s = ((const int*)ei)[e0];
            d = ((const int*)ei)[N_EDGES + e0];
        }
        int r = atomicAdd(&degi[d], 1);  // unique slot of edge within node d
        if (r < MAXD) csrE[d * MAXD + r] = s;
    }
}

// ---- MFMA GEMM body (operand-SWAPPED): out[node][n] via mfma(Wfrag, Xfrag).
// D layout col=lane&15 -> node = m0+mr per lane; row=quad*4+reg -> 4 CONSECUTIVE
// output cols per lane per n-tile => 8x 8B stores instead of 32x 2B.
// isd computed inline from degi (no precomputed array).
// mode 0: conv1 — Xin dtype per flags[0]. mode 1: conv2 — bf16 h_pre with fused
// BN(scale,shift)+relu prologue (vectorized coefficient loads).
static __device__ __forceinline__ void gemm_body(int bid, const void* __restrict__ Xin,
        const __hip_bfloat16* __restrict__ Wt, const int* __restrict__ degi,
        const int* __restrict__ flags, int mode,
        const float* __restrict__ bnscale, const float* __restrict__ bnshift,
        unsigned short* __restrict__ outb) {
    int wave = threadIdx.x >> 6, lane = threadIdx.x & 63;
    int quad = lane >> 4, mr = lane & 15;
    int m0 = bid * 64 + wave * 16;
    int node = m0 + mr;
    int row = (node < N_NODES) ? node : N_NODES - 1;
    short8 a[4];
    if (mode == 1) {
        const unsigned short* xb = (const unsigned short*)Xin;
#pragma unroll
        for (int t = 0; t < 4; ++t) {
            int k0 = t * 32 + quad * 8;
            ushort8 raw = *(const ushort8*)(xb + row * F + k0);
            f32x4 s0 = *(const f32x4*)(bnscale + k0);
            f32x4 s1 = *(const f32x4*)(bnscale + k0 + 4);
            f32x4 h0 = *(const f32x4*)(bnshift + k0);
            f32x4 h1 = *(const f32x4*)(bnshift + k0 + 4);
            short8 av;
#pragma unroll
            for (int j = 0; j < 4; ++j)
                av[j] = f2bf_s(fmaxf(bfu2f(raw[j]) * s0[j] + h0[j], 0.f));
#pragma unroll
            for (int j = 0; j < 4; ++j)
                av[4 + j] = f2bf_s(fmaxf(bfu2f(raw[4 + j]) * s1[j] + h1[j], 0.f));
            a[t] = av;
        }
    } else if (flags[0]) {
        const float* xf = (const float*)Xin;
#pragma unroll
        for (int t = 0; t < 4; ++t) {
            int off = row * F + t * 32 + quad * 8;
            f32x4 v0 = *(const f32x4*)(xf + off);
            f32x4 v1 = *(const f32x4*)(xf + off + 4);
            short8 av;
#pragma unroll
            for (int j = 0; j < 4; ++j) av[j] = f2bf_s(v0[j]);
#pragma unroll
            for (int j = 0; j < 4; ++j) av[4 + j] = f2bf_s(v1[j]);
            a[t] = av;
        }
    } else {
        const short* xb = (const short*)Xin;
#pragma unroll
        for (int t = 0; t < 4; ++t)
            a[t] = *(const short8*)(xb + row * F + t * 32 + quad * 8);
    }
    f32x4 acc[8];
    const short* wb = (const short*)Wt;
#pragma unroll
    for (int nt = 0; nt < 8; ++nt) {
        const short* wp = wb + (nt * 16 + mr) * F + quad * 8;
        f32x4 c = {0.f, 0.f, 0.f, 0.f};
        c = __builtin_amdgcn_mfma_f32_16x16x32_bf16(*(const short8*)(wp), a[0], c, 0, 0, 0);
        c = __builtin_amdgcn_mfma_f32_16x16x32_bf16(*(const short8*)(wp + 32), a[1], c, 0, 0, 0);
        c = __builtin_amdgcn_mfma_f32_16x16x32_bf16(*(const short8*)(wp + 64), a[2], c, 0, 0, 0);
        c = __builtin_amdgcn_mfma_f32_16x16x32_bf16(*(const short8*)(wp + 96), a[3], c, 0, 0, 0);
        acc[nt] = c;
    }
    if (node < N_NODES) {
        float sd = rsqrtf((float)degi[node] + 1.0f);
        unsigned short* op = outb + node * F;
#pragma unroll
        for (int nt = 0; nt < 8; ++nt) {
            ushortx4 r;
#pragma unroll
            for (int j = 0; j < 4; ++j) r[j] = f2bf_u(acc[nt][j] * sd);
            *(ushortx4*)(op + nt * 16 + quad * 4) = r;
        }
    }
}

__global__ __launch_bounds__(256) void k_gemm1(const void* __restrict__ X,
        const __hip_bfloat16* __restrict__ Wt1, const int* __restrict__ degi,
        const int* __restrict__ flags, unsigned short* __restrict__ outb) {
    gemm_body(blockIdx.x, X, Wt1, degi, flags, 0, nullptr, nullptr, outb);
}

__global__ __launch_bounds__(256) void k_gemm_bn(const void* __restrict__ Xin,
        const __hip_bfloat16* __restrict__ Wt, const int* __restrict__ degi,
        const int* __restrict__ flags, const float* __restrict__ bnscale,
        const float* __restrict__ bnshift, unsigned short* __restrict__ outb) {
    gemm_body(blockIdx.x, Xin, Wt, degi, flags, 1, bnscale, bnshift, outb);
}

// ---- shared aggregation core: wave=node, 4 groups of 16 lanes, 4-deep unrolled
// gather loop over the node's ELL row csrE[node*MAXD .. node*MAXD+deg). ----
static __device__ __forceinline__ void agg_accum(int node, int grp, int l16, int deg,
        const ushort8* __restrict__ vp, const int* __restrict__ csrE, float acc[8]) {
#pragma unroll
    for (int j = 0; j < 8; ++j) acc[j] = 0.f;
    if (grp == 0) {
        ushort8 u = vp[node * 16 + l16];  // self loop
#pragma unroll
        for (int j = 0; j < 8; ++j) acc[j] = bfu2f(u[j]);
    }
    int start = node * MAXD;
    int end = start + deg;
    int i = start + grp;
    for (; i + 12 < end; i += 16) {
        ushort8 u0 = vp[csrE[i] * 16 + l16];
        ushort8 u1 = vp[csrE[i + 4] * 16 + l16];
        ushort8 u2 = vp[csrE[i + 8] * 16 + l16];
        ushort8 u3 = vp[csrE[i + 12] * 16 + l16];
#pragma unroll
        for (int j = 0; j < 8; ++j)
            acc[j] += (bfu2f(u0[j]) + bfu2f(u1[j])) + (bfu2f(u2[j]) + bfu2f(u3[j]));
    }
    for (; i + 4 < end; i += 8) {
        ushort8 u0 = vp[csrE[i] * 16 + l16];
        ushort8 u1 = vp[csrE[i + 4] * 16 + l16];
#pragma unroll
        for (int j = 0; j < 8; ++j) acc[j] += bfu2f(u0[j]) + bfu2f(u1[j]);
    }
    for (; i < end; i += 4) {
        ushort8 u = vp[csrE[i] * 16 + l16];
#pragma unroll
        for (int j = 0; j < 8; ++j) acc[j] += bfu2f(u[j]);
    }
#pragma unroll
    for (int j = 0; j < 8; ++j) {
        acc[j] += __shfl_xor(acc[j], 16);
        acc[j] += __shfl_xor(acc[j], 32);
    }
}

// ---- aggregate1 + bias + FUSED BN partial stats (f32, pre-rounding):
// h_pre[d] = isd[d]*(A'[d] + sum A'[s]) + b1; per-block column sum/sumsq. ----
__global__ void k_agg1s(const unsigned short* __restrict__ val, const int* __restrict__ csrE,
                        const int* __restrict__ degi, const void* __restrict__ b1,
                        const int* __restrict__ flags, unsigned short* __restrict__ out,
                        float* __restrict__ partial) {
    __shared__ float lsum[4][128];
    __shared__ float lsq[4][128];
    int wv = threadIdx.x >> 6;
    int node = blockIdx.x * 4 + wv;
    int lane = threadIdx.x & 63;
    int grp = lane >> 4, l16 = lane & 15;
    if (node < N_NODES) {
        int dtrue = degi[node];
        int deg = (dtrue < MAXD) ? dtrue : MAXD;
        float acc[8];
        agg_accum(node, grp, l16, deg, (const ushort8*)val, csrE, acc);
        if (grp == 0) {
            float sd = rsqrtf((float)dtrue + 1.0f);
            int c0 = l16 * 8, f32 = flags[0];
            ushort8 r;
#pragma unroll
            for (int j = 0; j < 8; ++j) {
                float v = acc[j] * sd + loadF(b1, c0 + j, f32);
                r[j] = f2bf_u(v);
                lsum[wv][c0 + j] = v;
                lsq[wv][c0 + j] = v * v;
            }
            ((ushort8*)out)[node * 16 + l16] = r;
        }
    } else if (grp == 0) {
        int c0 = l16 * 8;
#pragma unroll
        for (int j = 0; j < 8; ++j) { lsum[wv][c0 + j] = 0.f; lsq[wv][c0 + j] = 0.f; }
    }
    __syncthreads();
    int t = threadIdx.x;
    if (t < 128) {
        float s = lsum[0][t] + lsum[1][t] + lsum[2][t] + lsum[3][t];
        float q = lsq[0][t] + lsq[1][t] + lsq[2][t] + lsq[3][t];
        partial[blockIdx.x * 256 + t] = s;
        partial[blockIdx.x * 256 + 128 + t] = q;
    }
}

// ---- fused BN reduce + coefficient prep: block c -> scale[c], shift[c] ----
__global__ void k_bnredprep(const float* __restrict__ partial, const void* __restrict__ gamma,
                            const void* __restrict__ beta, const int* __restrict__ flags,
                            float* __restrict__ scale, float* __restrict__ shift) {
    int c = blockIdx.x;  // 0..127
    float s = 0.f, q = 0.f;
    for (int b = threadIdx.x; b < AGG_BLOCKS; b += 256) {
        s += partial[b * 256 + c];
        q += partial[b * 256 + 128 + c];
    }
#pragma unroll
    for (int o = 32; o; o >>= 1) {
        s += __shfl_down(s, o);
        q += __shfl_down(q, o);
    }
    __shared__ float ws[4], wq[4];
    if ((threadIdx.x & 63) == 0) {
        ws[threadIdx.x >> 6] = s;
        wq[threadIdx.x >> 6] = q;
    }
    __syncthreads();
    if (threadIdx.x == 0) {
        float S = ws[0] + ws[1] + ws[2] + ws[3];
        float Q = wq[0] + wq[1] + wq[2] + wq[3];
        const float invN = 1.0f / (float)N_NODES;
        float m = S * invN;
        float var = Q * invN - m * m;
        int f32 = flags[0];
        float sc = loadF(gamma, c, f32) * rsqrtf(var + BN_EPS);
        scale[c] = sc;
        shift[c] = loadF(beta, c, f32) - m * sc;
    }
}

// ---- aggregate2 + epilogue: write mu[N,64] ++ log_std[N,64] in output dtype ----
__global__ void k_agg2(const unsigned short* __restrict__ val, const int* __restrict__ csrE,
                       const int* __restrict__ degi, const void* __restrict__ bmu,
                       const void* __restrict__ bls, const int* __restrict__ flags,
                       void* __restrict__ out) {
    int node = blockIdx.x * 4 + (threadIdx.x >> 6);
    if (node >= N_NODES) return;
    int lane = threadIdx.x & 63;
    int grp = lane >> 4, l16 = lane & 15;
    int dtrue = degi[node];
    int deg = (dtrue < MAXD) ? dtrue : MAXD;
    float acc[8];
    agg_accum(node, grp, l16, deg, (const ushort8*)val, csrE, acc);
    if (grp == 0) {
        float sd = rsqrtf((float)dtrue + 1.0f);
        int c0 = l16 * 8, f32 = flags[0];
        int hsel = (c0 >= L) ? 1 : 0;
        int cc = c0 - hsel * L;
        const void* bp = hsel ? bls : bmu;
        float o8[8];
#pragma unroll
        for (int j = 0; j < 8; ++j) o8[j] = acc[j] * sd + loadF(bp, cc + j, f32);
        long base_o = (long)hsel * (N_NODES * 64) + (long)node * 64 + cc;
        if (f32) {
            f32x4 r0 = {o8[0], o8[1], o8[2], o8[3]};
            f32x4 r1 = {o8[4], o8[5], o8[6], o8[7]};
            __builtin_nontemporal_store(r0, (f32x4*)((float*)out + base_o));
            __builtin_nontemporal_store(r1, (f32x4*)((float*)out + base_o + 4));
        } else {
            ushort8 r;
#pragma unroll
            for (int j = 0; j < 8; ++j) r[j] = f2bf_u(o8[j]);
            __builtin_nontemporal_store(r, (ushort8*)((__hip_bfloat16*)out + base_o));
        }
    }
}

extern "C" void kernel_launch(void* const* d_in, const int* in_sizes, int n_in,
                              void* d_out, int out_size, void* d_ws, size_t ws_size,
                              hipStream_t stream) {
    const void* x     = d_in[0];
    const void* ei    = d_in[1];
    const void* W1    = d_in[2];
    const void* b1    = d_in[3];
    const void* gamma = d_in[4];
    const void* beta  = d_in[5];
    const void* Wmu   = d_in[6];
    const void* bmu   = d_in[7];
    const void* Wls   = d_in[8];
    const void* bls   = d_in[9];

    int*   degi  = (int*)d_ws;                     // [50048] degrees
    float* stats = (float*)(degi + 50048);         // scale[128] shift[128] (+pad)
    int*   flags = (int*)(stats + 512);            // [16]
    int*   csrE  = flags + 16;                     // [50000*128] ELL neighbor lists
    __hip_bfloat16* Wt1 = (__hip_bfloat16*)(csrE + N_NODES * MAXD); // [16384]
    __hip_bfloat16* Wt2 = Wt1 + 16384;                              // [16384]
    unsigned short* Abf = (unsigned short*)(Wt2 + 16384);  // [N*128] bf16 A'
    unsigned short* Hpre = Abf + N_NODES * F;              // [N*128] bf16 h_pre
    float* partial = (float*)(Hpre + N_NODES * F);         // [AGG_BLOCKS*256]

    const int NT = 256;

    // zero degree counters (200KB, async, graph-capturable)
    hipMemsetAsync(degi, 0, 50048 * sizeof(int), stream);
    // prep: detect + weight transpose + edge degree/direct-ELL fill (one kernel)
    k_prep<<<65 + EDGE_BLOCKS, NT, 0, stream>>>(W1, Wmu, Wls, (const unsigned short*)x,
                                                ei, Wt1, Wt2, flags, degi, csrE);
    // conv1: A'1 = (x @ W1)*isd -> bf16
    k_gemm1<<<GEMM_BLOCKS, NT, 0, stream>>>(x, Wt1, degi, flags, Abf);
    // aggregate conv1 + bias + fused BN partial stats
    k_agg1s<<<AGG_BLOCKS, NT, 0, stream>>>(Abf, csrE, degi, b1, flags, Hpre, partial);
    // BN reduce + coefficient prep
    k_bnredprep<<<128, NT, 0, stream>>>(partial, gamma, beta, flags, stats, stats + 128);
    // conv2: A'2 = (relu(bn(h_pre)) @ [Wmu|Wls])*isd -> bf16 (reuses Abf)
    k_gemm_bn<<<GEMM_BLOCKS, NT, 0, stream>>>(Hpre, Wt2, degi, flags, stats, stats + 128, Abf);
    // aggregate conv2 + epilogue
    k_agg2<<<AGG_BLOCKS, NT, 0, stream>>>(Abf, csrE, degi, bmu, bls, flags, d_out);
}